// Round 2
// baseline (5164.577 us; speedup 1.0000x reference)
//
#include <hip/hip_runtime.h>
#include <hip/hip_bf16.h>
#include <cmath>

#define LATENT 6368
#define TSTEPS 64
#define NDATA 16
#define NPANEL 398   /* LATENT/16 */

typedef __attribute__((ext_vector_type(8))) short short8v;
typedef __attribute__((ext_vector_type(4))) float floatx4;

__device__ __forceinline__ unsigned short f2bf(float x) {
    union { float f; unsigned u; } c; c.f = x;
    unsigned r = (c.u + 0x7FFFu + ((c.u >> 16) & 1u)) >> 16;
    return (unsigned short)r;
}
__device__ __forceinline__ float bf2f(unsigned short h) {
    union { unsigned u; float f; } c; c.u = ((unsigned)h) << 16; return c.f;
}

// E = A - I split hi/lo bf16: Eh = bf16(E), El = bf16(E - Eh). Row-major [LATENT][LATENT].
__global__ __launch_bounds__(256) void convert_E2(const float* __restrict__ A,
                                                  unsigned short* __restrict__ Eh,
                                                  unsigned short* __restrict__ El,
                                                  int total8) {
    int t = blockIdx.x * blockDim.x + threadIdx.x;
    if (t >= total8) return;
    size_t idx = (size_t)t * 8u;
    const float4* src = reinterpret_cast<const float4*>(A + idx);
    float4 v0 = src[0];
    float4 v1 = src[1];
    float v[8] = {v0.x, v0.y, v0.z, v0.w, v1.x, v1.y, v1.z, v1.w};
    // diagonal global indices are multiples of LATENT+1 = 6369
    unsigned q = (unsigned)(idx % 6369u);
    unsigned jd = (6369u - q) % 6369u;
    if (jd < 8u) v[jd] -= 1.0f;
    union { short8v s; unsigned short u[8]; } oh, ol;
#pragma unroll
    for (int j = 0; j < 8; ++j) {
        unsigned short hb = f2bf(v[j]);
        oh.u[j] = hb;
        ol.u[j] = f2bf(v[j] - bf2f(hb));
    }
    *reinterpret_cast<short8v*>(Eh + idx) = oh.s;
    *reinterpret_cast<short8v*>(El + idx) = ol.s;
}

// T0[r][b] = theta0[r] f32; TT*h/l[n][r] = hi/lo bf16 (n<8), rows 8..15 zeroed in all 4 TT buffers.
__global__ __launch_bounds__(256) void init_theta(const float* __restrict__ th0,
                                                  float* __restrict__ T0,
                                                  unsigned short* __restrict__ TT0h,
                                                  unsigned short* __restrict__ TT0l,
                                                  unsigned short* __restrict__ TT1h,
                                                  unsigned short* __restrict__ TT1l) {
    int r = blockIdx.x * blockDim.x + threadIdx.x;
    if (r >= LATENT) return;
    float v = th0[r];
#pragma unroll
    for (int b = 0; b < 8; ++b) T0[r * 8 + b] = v;
    unsigned short hb = f2bf(v);
    unsigned short lb = f2bf(v - bf2f(hb));
#pragma unroll
    for (int n = 0; n < 8; ++n) { TT0h[n * LATENT + r] = hb; TT0l[n * LATENT + r] = lb; }
#pragma unroll
    for (int n = 8; n < 16; ++n) {
        TT0h[n * LATENT + r] = 0; TT0l[n * LATENT + r] = 0;
        TT1h[n * LATENT + r] = 0; TT1l[n * LATENT + r] = 0;
    }
}

// One launch per step s (128 threads/block):
//   blocks 0..397 : Theta_{s+1} = Theta_s + E@Theta_s + B@u_s  (16 rows each, 2 waves split K)
//   block  398    : MLP for step s-1 using Theta_s
// Feedback lag: u_s needs mean_{s-2} -> written two launches ago -> no intra-kernel sync.
template<bool USE_E>
__global__ __launch_bounds__(128) void step_kernel(
    const unsigned short* __restrict__ Eh,
    const unsigned short* __restrict__ El,
    const float* __restrict__ Af,
    const unsigned short* __restrict__ TThc,   // [16][LATENT] bf16 hi (cols 8..15 zero)
    const unsigned short* __restrict__ TTlc,   // [16][LATENT] bf16 lo
    const float* __restrict__ Tcur,            // [LATENT][8] f32
    float* __restrict__ Tnxt,
    unsigned short* __restrict__ TThn,
    unsigned short* __restrict__ TTln,
    const float* __restrict__ Bmat,            // [LATENT][17]
    const float* __restrict__ xs,              // [8][64][16]
    const float* __restrict__ ts,              // [8][64]
    const float* __restrict__ mread,           // mean_{s-2} [8][16]
    float* __restrict__ mwrite,                // mean_{s-1} [8][16]
    float* __restrict__ ys,                    // [8][64][32]
    int s, int do_matvec, int do_mlp)
{
    int tid = threadIdx.x;
    if ((int)blockIdx.x < NPANEL) {
        if (!do_matvec) return;
        __shared__ float u[17][8];
        __shared__ float red[2][16][16];
        for (int t = tid; t < 136; t += 128) {
            int b = t & 7;
            int j = t >> 3;
            float tc = ts[b * TSTEPS + s];
            float tp = (s == 0) ? -ts[b * TSTEPS + 1] : ts[b * TSTEPS + s - 1];
            float val;
            if (j == 0) {
                val = tc - tp;
            } else {
                int d = j - 1;
                float xp = (s < 2) ? xs[(b * TSTEPS) * NDATA + d]
                                   : mread[b * NDATA + d];
                val = xs[(b * TSTEPS + s) * NDATA + d] - xp;
            }
            u[j][b] = val;
        }
        __syncthreads();
        int wave = tid >> 6;
        int lane = tid & 63;
        int rowl = lane & 15;   // A row within panel == B col (batch)
        int kgrp = lane >> 4;   // 0..3
        int row = blockIdx.x * 16 + rowl;
        int cstart = wave * 100;
        int cend = cstart + 100; if (cend > 199) cend = 199;  // 199 K-chunks of 32
        floatx4 acc = {0.f, 0.f, 0.f, 0.f};
        for (int c = cstart; c < cend; ++c) {
            int k = c * 32 + kgrp * 8;
            size_t eoff = (size_t)row * LATENT + k;
            short8v ehf, elf;
            if (USE_E) {
                ehf = *reinterpret_cast<const short8v*>(Eh + eoff);
                elf = *reinterpret_cast<const short8v*>(El + eoff);
            } else {
                const float* ap = Af + eoff;
                float v[8];
#pragma unroll
                for (int j = 0; j < 8; ++j) v[j] = ap[j];
                int jd = row - k;
                if (jd >= 0 && jd < 8) v[jd] -= 1.0f;
                union { short8v sv; unsigned short us[8]; } ch, cl;
#pragma unroll
                for (int j = 0; j < 8; ++j) {
                    unsigned short hb = f2bf(v[j]);
                    ch.us[j] = hb;
                    cl.us[j] = f2bf(v[j] - bf2f(hb));
                }
                ehf = ch.sv; elf = cl.sv;
            }
            size_t toff = (size_t)rowl * LATENT + k;
            short8v thf = *reinterpret_cast<const short8v*>(TThc + toff);
            short8v tlf = *reinterpret_cast<const short8v*>(TTlc + toff);
            acc = __builtin_amdgcn_mfma_f32_16x16x32_bf16(ehf, thf, acc, 0, 0, 0);
            acc = __builtin_amdgcn_mfma_f32_16x16x32_bf16(ehf, tlf, acc, 0, 0, 0);
            acc = __builtin_amdgcn_mfma_f32_16x16x32_bf16(elf, thf, acc, 0, 0, 0);
        }
        // C/D layout: col = lane&15, row = (lane>>4)*4 + reg
#pragma unroll
        for (int r = 0; r < 4; ++r) red[wave][kgrp * 4 + r][rowl] = acc[r];
        __syncthreads();
        int n = tid & 15;
        if (n < 8) {
            for (int m = tid >> 4; m < 16; m += 8) {
                float sum = red[0][m][n] + red[1][m][n];
                int rr = blockIdx.x * 16 + m;
                float val = Tcur[rr * 8 + n] + sum;
                const float* Brow = Bmat + rr * 17;
#pragma unroll
                for (int j = 0; j < 17; ++j) val += Brow[j] * u[j][n];
                Tnxt[rr * 8 + n] = val;
                unsigned short hb = f2bf(val);
                TThn[n * LATENT + rr] = hb;
                TTln[n * LATENT + rr] = f2bf(val - bf2f(hb));
            }
        }
    } else {
        if (!do_mlp) return;
        int i = s - 1;
        __shared__ float h0s[8][64];
        __shared__ float h1s[8][64];
        int w = tid >> 6;       // 0..1
        int lane = tid & 63;
        for (int it = 0; it < 4; ++it) {
            int b = w * 4 + it;
            float tc = ts[b * TSTEPS + i];
            float tp = (i == 0) ? -ts[b * TSTEPS + 1] : ts[b * TSTEPS + i - 1];
            float rin = 2.f * tc - tp;   // root_in = t + delta_t
            // layer 0: W0=th[0:64], b0=th[64:128]
            float w0 = Tcur[(size_t)lane * 8 + b];
            float b0 = Tcur[(size_t)(64 + lane) * 8 + b];
            float h0 = fmaxf(w0 * rin + b0, 0.f);
            h0s[b][lane] = h0;
            __syncthreads();
            // layer 1: W1=th[128:4224] (64x64), b1=th[4224:4288]
            float h1 = Tcur[(size_t)(4224 + lane) * 8 + b];
#pragma unroll 8
            for (int k = 0; k < 64; ++k)
                h1 += Tcur[(size_t)(128 + lane * 64 + k) * 8 + b] * h0s[b][k];
            h1 = fmaxf(h1, 0.f);
            h1s[b][lane] = h1;
            __syncthreads();
            // layer 2: W2=th[4288:6336] (32x64), b2=th[6336:6368]
            if (lane < 32) {
                float o = Tcur[(size_t)(6336 + lane) * 8 + b];
#pragma unroll 8
                for (int k = 0; k < 64; ++k)
                    o += Tcur[(size_t)(4288 + lane * 64 + k) * 8 + b] * h1s[b][k];
                float z = tanhf(o);
                float res;
                if (lane < 16) { res = z; mwrite[b * NDATA + lane] = z; }
                else           { res = log1pf(expf(z)); }  // softplus(tanh)
                ys[(size_t)b * (TSTEPS * 32) + (size_t)i * 32 + lane] = res;
            }
            __syncthreads();
        }
    }
}

extern "C" void kernel_launch(void* const* d_in, const int* in_sizes, int n_in,
                              void* d_out, int out_size, void* d_ws, size_t ws_size,
                              hipStream_t stream) {
    const float* xs  = (const float*)d_in[0];
    const float* ts  = (const float*)d_in[1];
    const float* A   = (const float*)d_in[2];
    const float* Bm  = (const float*)d_in[3];
    const float* th0 = (const float*)d_in[4];
    float* ys = (float*)d_out;

    char* ws = (char*)d_ws;
    size_t off = 0;
    auto alloc = [&](size_t bytes) {
        void* p = ws + off;
        off += (bytes + 255) & ~(size_t)255;
        return p;
    };
    float* T0 = (float*)alloc((size_t)LATENT * 8 * sizeof(float));
    float* T1 = (float*)alloc((size_t)LATENT * 8 * sizeof(float));
    unsigned short* TT0h = (unsigned short*)alloc((size_t)16 * LATENT * 2);
    unsigned short* TT0l = (unsigned short*)alloc((size_t)16 * LATENT * 2);
    unsigned short* TT1h = (unsigned short*)alloc((size_t)16 * LATENT * 2);
    unsigned short* TT1l = (unsigned short*)alloc((size_t)16 * LATENT * 2);
    float* mb = (float*)alloc(2 * 8 * 16 * sizeof(float));
    size_t Ebytes = (size_t)LATENT * LATENT * 2;
    bool useE = (off + 2 * Ebytes + 512) <= ws_size;
    unsigned short* EhP = nullptr;
    unsigned short* ElP = nullptr;
    if (useE) {
        EhP = (unsigned short*)alloc(Ebytes);
        ElP = (unsigned short*)alloc(Ebytes);
        int total8 = LATENT * LATENT / 8;
        convert_E2<<<dim3((total8 + 255) / 256), dim3(256), 0, stream>>>(A, EhP, ElP, total8);
    }
    init_theta<<<dim3((LATENT + 255) / 256), dim3(256), 0, stream>>>(th0, T0, TT0h, TT0l, TT1h, TT1l);
    float* T[2] = {T0, T1};
    unsigned short* TTh[2] = {TT0h, TT1h};
    unsigned short* TTl[2] = {TT0l, TT1l};
    for (int s = 0; s <= TSTEPS; ++s) {
        int cur = s & 1, nxt = cur ^ 1;
        float* mread  = mb + (s & 1) * 128;          // mean_{s-2} slot
        float* mwrite = mb + ((s & 1) ^ 1) * 128;    // mean_{s-1} slot
        int dmv = (s < TSTEPS) ? 1 : 0;
        int dml = (s >= 1) ? 1 : 0;
        if (useE)
            step_kernel<true><<<dim3(NPANEL + 1), dim3(128), 0, stream>>>(
                EhP, ElP, A, TTh[cur], TTl[cur], T[cur], T[nxt], TTh[nxt], TTl[nxt],
                Bm, xs, ts, mread, mwrite, ys, s, dmv, dml);
        else
            step_kernel<false><<<dim3(NPANEL + 1), dim3(128), 0, stream>>>(
                EhP, ElP, A, TTh[cur], TTl[cur], T[cur], T[nxt], TTh[nxt], TTl[nxt],
                Bm, xs, ts, mread, mwrite, ys, s, dmv, dml);
    }
    (void)in_sizes; (void)n_in; (void)out_size;
}

// Round 3
// 3847.815 us; speedup vs baseline: 1.3422x; 1.3422x over previous
//
#include <hip/hip_runtime.h>
#include <hip/hip_bf16.h>
#include <cmath>

#define LATENT 6368
#define TSTEPS 64
#define NDATA 16
#define NPANEL 398   /* LATENT/16 */
#define KSPLIT 8
#define NCHUNK 199   /* LATENT/32 */
#define CPS 25       /* ceil(199/8) chunks per slice */

typedef __attribute__((ext_vector_type(8))) short short8v;
typedef __attribute__((ext_vector_type(4))) float floatx4;

__device__ __forceinline__ unsigned short f2bf(float x) {
    union { float f; unsigned u; } c; c.f = x;
    unsigned r = (c.u + 0x7FFFu + ((c.u >> 16) & 1u)) >> 16;
    return (unsigned short)r;
}
__device__ __forceinline__ float bf2f(unsigned short h) {
    union { unsigned u; float f; } c; c.u = ((unsigned)h) << 16; return c.f;
}

// E = A - I split hi/lo bf16: Eh = bf16(E), El = bf16(E - Eh). Row-major [LATENT][LATENT].
__global__ __launch_bounds__(256) void convert_E2(const float* __restrict__ A,
                                                  unsigned short* __restrict__ Eh,
                                                  unsigned short* __restrict__ El,
                                                  int total8) {
    int t = blockIdx.x * blockDim.x + threadIdx.x;
    if (t >= total8) return;
    size_t idx = (size_t)t * 8u;
    const float4* src = reinterpret_cast<const float4*>(A + idx);
    float4 v0 = src[0];
    float4 v1 = src[1];
    float v[8] = {v0.x, v0.y, v0.z, v0.w, v1.x, v1.y, v1.z, v1.w};
    unsigned q = (unsigned)(idx % 6369u);       // diag at multiples of LATENT+1
    unsigned jd = (6369u - q) % 6369u;
    if (jd < 8u) v[jd] -= 1.0f;
    union { short8v s; unsigned short u[8]; } oh, ol;
#pragma unroll
    for (int j = 0; j < 8; ++j) {
        unsigned short hb = f2bf(v[j]);
        oh.u[j] = hb;
        ol.u[j] = f2bf(v[j] - bf2f(hb));
    }
    *reinterpret_cast<short8v*>(Eh + idx) = oh.s;
    *reinterpret_cast<short8v*>(El + idx) = ol.s;
}

__global__ __launch_bounds__(256) void init_theta(const float* __restrict__ th0,
                                                  float* __restrict__ T0,
                                                  unsigned short* __restrict__ TT0h,
                                                  unsigned short* __restrict__ TT0l,
                                                  unsigned short* __restrict__ TT1h,
                                                  unsigned short* __restrict__ TT1l) {
    int r = blockIdx.x * blockDim.x + threadIdx.x;
    if (r >= LATENT) return;
    float v = th0[r];
#pragma unroll
    for (int b = 0; b < 8; ++b) T0[r * 8 + b] = v;
    unsigned short hb = f2bf(v);
    unsigned short lb = f2bf(v - bf2f(hb));
#pragma unroll
    for (int n = 0; n < 8; ++n) { TT0h[n * LATENT + r] = hb; TT0l[n * LATENT + r] = lb; }
#pragma unroll
    for (int n = 8; n < 16; ++n) {
        TT0h[n * LATENT + r] = 0; TT0l[n * LATENT + r] = 0;
        TT1h[n * LATENT + r] = 0; TT1l[n * LATENT + r] = 0;
    }
}

// Split-K partial: block (p, si) computes rows p*16..p*16+15, K-chunks [si*25, min(+25,199))
// P[((p*8+si)*16+m)*8+n] = partial (E@Theta)[row][batch]
template<bool USE_E>
__global__ __launch_bounds__(128) void partial_kernel(
    const unsigned short* __restrict__ Eh,
    const unsigned short* __restrict__ El,
    const float* __restrict__ Af,
    const unsigned short* __restrict__ TThc,   // [16][LATENT] bf16 hi (rows 8..15 zero)
    const unsigned short* __restrict__ TTlc,   // [16][LATENT] bf16 lo
    float* __restrict__ P)
{
    int blk = blockIdx.x;
    int p  = blk >> 3;
    int si = blk & 7;
    int tid = threadIdx.x;
    int wave = tid >> 6;
    int lane = tid & 63;
    int rowl = lane & 15;
    int kgrp = lane >> 4;
    int row = p * 16 + rowl;
    int c0 = si * CPS;
    int c1 = c0 + CPS; if (c1 > NCHUNK) c1 = NCHUNK;
    int nch = c1 - c0;
    int half = (nch + 1) >> 1;
    int cs = c0 + wave * half;
    int ce = cs + half; if (ce > c1) ce = c1;
    floatx4 acc = {0.f, 0.f, 0.f, 0.f};
    for (int c = cs; c < ce; ++c) {
        int k = c * 32 + kgrp * 8;
        size_t eoff = (size_t)row * LATENT + k;
        short8v ehf, elf;
        if (USE_E) {
            ehf = *reinterpret_cast<const short8v*>(Eh + eoff);
            elf = *reinterpret_cast<const short8v*>(El + eoff);
        } else {
            const float* ap = Af + eoff;
            float v[8];
#pragma unroll
            for (int j = 0; j < 8; ++j) v[j] = ap[j];
            int jd = row - k;
            if (jd >= 0 && jd < 8) v[jd] -= 1.0f;
            union { short8v sv; unsigned short us[8]; } ch, cl;
#pragma unroll
            for (int j = 0; j < 8; ++j) {
                unsigned short hb = f2bf(v[j]);
                ch.us[j] = hb;
                cl.us[j] = f2bf(v[j] - bf2f(hb));
            }
            ehf = ch.sv; elf = cl.sv;
        }
        size_t toff = (size_t)rowl * LATENT + k;
        short8v thf = *reinterpret_cast<const short8v*>(TThc + toff);
        short8v tlf = *reinterpret_cast<const short8v*>(TTlc + toff);
        acc = __builtin_amdgcn_mfma_f32_16x16x32_bf16(ehf, thf, acc, 0, 0, 0);
        acc = __builtin_amdgcn_mfma_f32_16x16x32_bf16(ehf, tlf, acc, 0, 0, 0);
        acc = __builtin_amdgcn_mfma_f32_16x16x32_bf16(elf, thf, acc, 0, 0, 0);
    }
    __shared__ float red[2][16][16];
    // C/D layout: col = lane&15, row = (lane>>4)*4 + reg
#pragma unroll
    for (int r = 0; r < 4; ++r) red[wave][kgrp * 4 + r][rowl] = acc[r];
    __syncthreads();
    int nn = tid & 15;
    if (nn < 8) {
        for (int mm = tid >> 4; mm < 16; mm += 8) {
            float s2 = red[0][mm][nn] + red[1][mm][nn];
            P[((size_t)(p * 8 + si) * 16 + mm) * 8 + nn] = s2;
        }
    }
}

// Combine: blocks 0..198 finish Theta_{s+1}; block 199 runs the MLP for step s-1.
__global__ __launch_bounds__(256) void combine_kernel(
    const float* __restrict__ P,
    const float* __restrict__ Tcur,            // [LATENT][8] f32 (= theta_s)
    float* __restrict__ Tnxt,
    unsigned short* __restrict__ TThn,
    unsigned short* __restrict__ TTln,
    const float* __restrict__ Bmat,            // [LATENT][17]
    const float* __restrict__ xs,              // [8][64][16]
    const float* __restrict__ ts,              // [8][64]
    const float* __restrict__ mread,           // mean_{s-2} [8][16]
    float* __restrict__ mwrite,                // mean_{s-1} [8][16]
    float* __restrict__ ys,                    // [8][64][32]
    int s, int do_matvec, int do_mlp)
{
    int tid = threadIdx.x;
    if ((int)blockIdx.x < 199) {
        if (!do_matvec) return;
        __shared__ float u[17][8];
        if (tid < 136) {
            int b = tid & 7;
            int j = tid >> 3;
            float tc = ts[b * TSTEPS + s];
            float tp = (s == 0) ? -ts[b * TSTEPS + 1] : ts[b * TSTEPS + s - 1];
            float val;
            if (j == 0) {
                val = tc - tp;
            } else {
                int d = j - 1;
                float xp = (s < 2) ? xs[(b * TSTEPS) * NDATA + d]
                                   : mread[b * NDATA + d];
                val = xs[(b * TSTEPS + s) * NDATA + d] - xp;
            }
            u[j][b] = val;
        }
        __syncthreads();
        int idx = blockIdx.x * 256 + tid;      // 199*256 = 50944 = LATENT*8
        int r = idx >> 3;
        int n = idx & 7;
        int pp = r >> 4, mm = r & 15;
        const float* Pb = P + ((size_t)pp * 8) * 128 + mm * 8 + n;
        float sum = 0.f;
#pragma unroll
        for (int si = 0; si < KSPLIT; ++si) sum += Pb[si * 128];
        float val = Tcur[r * 8 + n] + sum;
        const float* Brow = Bmat + r * 17;
#pragma unroll
        for (int j = 0; j < 17; ++j) val += Brow[j] * u[j][n];
        Tnxt[r * 8 + n] = val;
        unsigned short hb = f2bf(val);
        TThn[n * LATENT + r] = hb;
        TTln[n * LATENT + r] = f2bf(val - bf2f(hb));
    } else {
        if (!do_mlp) return;
        int i = s - 1;
        __shared__ float h0s[8][64];
        __shared__ float h1s[8][64];
        int w = tid >> 6;       // 0..3
        int lane = tid & 63;
        for (int it = 0; it < 2; ++it) {
            int b = w * 2 + it;
            float tc = ts[b * TSTEPS + i];
            float tp = (i == 0) ? -ts[b * TSTEPS + 1] : ts[b * TSTEPS + i - 1];
            float rin = 2.f * tc - tp;   // root_in = t + delta_t
            float w0 = Tcur[(size_t)lane * 8 + b];
            float b0 = Tcur[(size_t)(64 + lane) * 8 + b];
            float h0 = fmaxf(w0 * rin + b0, 0.f);
            h0s[b][lane] = h0;
            __syncthreads();
            float h1 = Tcur[(size_t)(4224 + lane) * 8 + b];
#pragma unroll 8
            for (int k = 0; k < 64; ++k)
                h1 += Tcur[(size_t)(128 + lane * 64 + k) * 8 + b] * h0s[b][k];
            h1 = fmaxf(h1, 0.f);
            h1s[b][lane] = h1;
            __syncthreads();
            if (lane < 32) {
                float o = Tcur[(size_t)(6336 + lane) * 8 + b];
#pragma unroll 8
                for (int k = 0; k < 64; ++k)
                    o += Tcur[(size_t)(4288 + lane * 64 + k) * 8 + b] * h1s[b][k];
                float z = tanhf(o);
                float res;
                if (lane < 16) { res = z; mwrite[b * NDATA + lane] = z; }
                else           { res = log1pf(expf(z)); }  // softplus(tanh)
                ys[(size_t)b * (TSTEPS * 32) + (size_t)i * 32 + lane] = res;
            }
            __syncthreads();
        }
    }
}

extern "C" void kernel_launch(void* const* d_in, const int* in_sizes, int n_in,
                              void* d_out, int out_size, void* d_ws, size_t ws_size,
                              hipStream_t stream) {
    const float* xs  = (const float*)d_in[0];
    const float* ts  = (const float*)d_in[1];
    const float* A   = (const float*)d_in[2];
    const float* Bm  = (const float*)d_in[3];
    const float* th0 = (const float*)d_in[4];
    float* ys = (float*)d_out;

    char* ws = (char*)d_ws;
    size_t off = 0;
    auto alloc = [&](size_t bytes) {
        void* p = ws + off;
        off += (bytes + 255) & ~(size_t)255;
        return p;
    };
    float* T0 = (float*)alloc((size_t)LATENT * 8 * sizeof(float));
    float* T1 = (float*)alloc((size_t)LATENT * 8 * sizeof(float));
    unsigned short* TT0h = (unsigned short*)alloc((size_t)16 * LATENT * 2);
    unsigned short* TT0l = (unsigned short*)alloc((size_t)16 * LATENT * 2);
    unsigned short* TT1h = (unsigned short*)alloc((size_t)16 * LATENT * 2);
    unsigned short* TT1l = (unsigned short*)alloc((size_t)16 * LATENT * 2);
    float* mb = (float*)alloc(2 * 8 * 16 * sizeof(float));
    float* P  = (float*)alloc((size_t)NPANEL * KSPLIT * 16 * 8 * sizeof(float));
    size_t Ebytes = (size_t)LATENT * LATENT * 2;
    bool useE = (off + 2 * Ebytes + 512) <= ws_size;
    unsigned short* EhP = nullptr;
    unsigned short* ElP = nullptr;
    if (useE) {
        EhP = (unsigned short*)alloc(Ebytes);
        ElP = (unsigned short*)alloc(Ebytes);
        int total8 = LATENT * LATENT / 8;
        convert_E2<<<dim3((total8 + 255) / 256), dim3(256), 0, stream>>>(A, EhP, ElP, total8);
    }
    init_theta<<<dim3((LATENT + 255) / 256), dim3(256), 0, stream>>>(th0, T0, TT0h, TT0l, TT1h, TT1l);
    float* T[2] = {T0, T1};
    unsigned short* TTh[2] = {TT0h, TT1h};
    unsigned short* TTl[2] = {TT0l, TT1l};
    for (int s = 0; s <= TSTEPS; ++s) {
        int cur = s & 1, nxt = cur ^ 1;
        float* mread  = mb + (s & 1) * 128;          // mean_{s-2} slot
        float* mwrite = mb + ((s & 1) ^ 1) * 128;    // mean_{s-1} slot
        int dmv = (s < TSTEPS) ? 1 : 0;
        int dml = (s >= 1) ? 1 : 0;
        if (dmv) {
            if (useE)
                partial_kernel<true><<<dim3(NPANEL * KSPLIT), dim3(128), 0, stream>>>(
                    EhP, ElP, A, TTh[cur], TTl[cur], P);
            else
                partial_kernel<false><<<dim3(NPANEL * KSPLIT), dim3(128), 0, stream>>>(
                    EhP, ElP, A, TTh[cur], TTl[cur], P);
        }
        combine_kernel<<<dim3(200), dim3(256), 0, stream>>>(
            P, T[cur], T[nxt], TTh[nxt], TTl[nxt],
            Bm, xs, ts, mread, mwrite, ys, s, dmv, dml);
    }
    (void)in_sizes; (void)n_in; (void)out_size;
}